// Round 17
// baseline (136.875 us; speedup 1.0000x reference)
//
#include <hip/hip_runtime.h>
#include <hip/hip_fp16.h>

// NCN, fully wave-local: 1024 independent waves = chains (b,h,c). ZERO
// barriers. R16: within-wave software pipeline — gemm(ch+1) MFMAs are issued
// BEFORE scan(ch)'s serial 32-step tanh chain and retire in its latency
// shadow (sched_barrier(0) pins them); scatter+mix-load run after. y handoff
// in d_ws f16 (in place across modules, vmcnt(0) at module boundary orders
// same-wave RAW); module 3 writes f32 directly to d_out. Fallback small-ws:
// y f16 in d_out first-halves + expand. MFMA mapping = R8-validated; scan
// carries u = y*log2e (chain: add -> v_exp -> add -> rcp -> fma).

typedef _Float16 f16;
typedef _Float16 half8 __attribute__((ext_vector_type(8)));
typedef _Float16 half4v __attribute__((ext_vector_type(4)));
typedef float f32x4 __attribute__((ext_vector_type(4)));
typedef unsigned uint4v __attribute__((ext_vector_type(4)));

constexpr int B = 8, T = 4096, D = 1024, H = 16, DH = 64, NC = 8, NM = 4;
constexpr int KS = 32;               // scan steps per chunk
constexpr int NCH = (T / NC) / KS;   // 16 chunks per module
constexpr size_t YWS_BYTES = (size_t)B * T * 2048;   // 64 MiB
constexpr float L2E = 1.44269504088896340736f;

__device__ __forceinline__ float exp2_fast(float v) {
  float r;
  asm("v_exp_f32 %0, %1" : "=v"(r) : "v"(v));
  return r;
}

template <bool WS>
__global__ __launch_bounds__(256, 1)
void ncn_wave(const float* __restrict__ x, const float* __restrict__ xa,
              const float* __restrict__ w, float* __restrict__ out,
              unsigned char* __restrict__ ybuf) {
  constexpr int YROW = WS ? 2048 : 4096;   // y f16 row stride
  __shared__ __align__(16) unsigned char YST[4][4096];   // per-wave 32x128B
  __shared__ __align__(16) unsigned char MXS[4][8192];   // per-wave [e][128B]

  const int tid = threadIdx.x, lane = tid & 63, wv = tid >> 6;
  const int g = blockIdx.x * 4 + wv;        // chain id (b,h,c)
  const int c = g & 7, h = (g >> 3) & 15, b = g >> 7;
  const int lr = lane & 15, lg = lane >> 4;

  unsigned char* const yst = YST[wv];
  unsigned char* const mxs = MXS[wv];
  const unsigned char* const xb = (const unsigned char*)x + (size_t)b * T * 4096;
  unsigned char* const ob = (unsigned char*)out + (size_t)b * T * 4096;
  unsigned char* const yb = ybuf + (size_t)b * T * YROW;

  float y = xa[((size_t)b * NC + c) * D + h * DH + lane];
  float u = y * L2E;                        // carried: arg * log2(e)

  uint4v pf[8];
  half8 Wf[4][2];
  float mixf[KS];
  f32x4 acc[2][4];

  auto prefetch = [&](int m, int ch) {      // own rows of chunk ch -> pf
    const int J0 = ch * KS;
    if (m == 0) {                           // x f32: 32 rows x 256B
#pragma unroll
      for (int i = 0; i < 8; ++i) {
        const int lt = i * 4 + (lane >> 4);
        const int t = (J0 + lt) * 8 + c;
        pf[i] = *(const uint4v*)(xb + (size_t)t * 4096 + h * 256 + (lane & 15) * 16);
      }
    } else {                                // y f16: 32 rows x 128B
#pragma unroll
      for (int i = 0; i < 4; ++i) {
        const int lt = i * 8 + (lane >> 3);
        const int t = (J0 + lt) * 8 + c;
        pf[i] = *(const uint4v*)(yb + (size_t)t * YROW + h * 128 + (lane & 7) * 16);
      }
    }
  };
  auto stage = [&](int m) {                 // pf -> yst (swizzled f16 rows)
    if (m == 0) {
#pragma unroll
      for (int i = 0; i < 8; ++i) {
        const int lt = i * 4 + (lane >> 4);
        const f32x4 v = __builtin_bit_cast(f32x4, pf[i]);
        const __half2 p0 = __floats2half2_rn(v.x, v.y);
        const __half2 p1 = __floats2half2_rn(v.z, v.w);
        uint2 pk;
        pk.x = __builtin_bit_cast(unsigned, p0);
        pk.y = __builtin_bit_cast(unsigned, p1);
        *(uint2*)(yst + lt * 128 + (((lane & 15) * 8) ^ ((lt & 7) << 4))) = pk;
      }
    } else {
#pragma unroll
      for (int i = 0; i < 4; ++i) {
        const int lt = i * 8 + (lane >> 3);
        *(uint4v*)(yst + lt * 128 + (((lane & 7) * 16) ^ ((lt & 7) << 4))) = pf[i];
      }
    }
  };
  auto gemm_issue = [&]() {                 // yst -> acc (16 MFMA)
#pragma unroll
    for (int tq = 0; tq < 2; ++tq) {
      half8 Xf[2];
#pragma unroll
      for (int kt = 0; kt < 2; ++kt) {
        const int lt = tq * 16 + lr;
        Xf[kt] = *(const half8*)(yst + lt * 128 +
                                 ((kt * 64 + lg * 16) ^ ((lt & 7) << 4)));
      }
#pragma unroll
      for (int it = 0; it < 4; ++it) acc[tq][it] = (f32x4){0.f, 0.f, 0.f, 0.f};
#pragma unroll
      for (int kt = 0; kt < 2; ++kt)
#pragma unroll
        for (int it = 0; it < 4; ++it)
          acc[tq][it] = __builtin_amdgcn_mfma_f32_16x16x32_f16(
              Xf[kt], Wf[it][kt], acc[tq][it], 0, 0, 0);
    }
  };
  auto scatter = [&]() {                    // acc -> MX (e-major, swizzled)
#pragma unroll
    for (int tq = 0; tq < 2; ++tq)
#pragma unroll
      for (int it = 0; it < 4; ++it) {
        const int e = it * 16 + lr;
        const __half2 p0 = __floats2half2_rn(acc[tq][it].x, acc[tq][it].y);
        const __half2 p1 = __floats2half2_rn(acc[tq][it].z, acc[tq][it].w);
        uint2 pk;
        pk.x = __builtin_bit_cast(unsigned, p0);
        pk.y = __builtin_bit_cast(unsigned, p1);
        *(uint2*)(mxs + e * 128 + ((tq * 32 + lg * 8) ^ ((e & 7) << 4))) = pk;
      }
  };
  auto mixload = [&]() {                    // MX -> mixf (off-chain cvt *L2E)
    half8 mxr[4];
#pragma unroll
    for (int k16 = 0; k16 < 4; ++k16)
      mxr[k16] = *(const half8*)(mxs + lane * 128 +
                                 ((k16 * 16) ^ ((lane & 7) << 4)));
#pragma unroll
    for (int k = 0; k < KS; ++k) mixf[k] = (float)mxr[k >> 3][k & 7] * L2E;
  };
  auto scan = [&](int m, int ch) {          // serial 32-step tanh chain
    const int t0 = ch * KS * 8 + c;
    if (m < 3 || !WS) {
      unsigned char* sp = yb + (size_t)t0 * YROW + h * 128 + 2 * lane;
#pragma unroll
      for (int k = 0; k < KS; ++k) {
        const float z = u + mixf[k];
        const float E = exp2_fast(z);
        const float r = __builtin_amdgcn_rcpf(E + 1.0f);
        y = fmaf(r, -2.0f, 1.0f);
        u = fmaf(r, -2.0f * L2E, L2E);
        *(__half*)sp = __float2half_rn(y);
        sp += (size_t)8 * YROW;
      }
    } else {
      unsigned char* sp = ob + (size_t)t0 * 4096 + h * 256 + 4 * lane;
#pragma unroll
      for (int k = 0; k < KS; ++k) {
        const float z = u + mixf[k];
        const float E = exp2_fast(z);
        const float r = __builtin_amdgcn_rcpf(E + 1.0f);
        y = fmaf(r, -2.0f, 1.0f);
        u = fmaf(r, -2.0f * L2E, L2E);
        *(float*)sp = y;
        sp += (size_t)8 * 4096;
      }
    }
  };

  for (int m = 0; m < NM; ++m) {
    // W fragments (R8-validated): Wf[it][kt][j] = W[m,h, kt*32+lg*8+j, it*16+lr]
    const float* wh = w + ((size_t)m * H + h) * DH * DH;
#pragma unroll
    for (int it = 0; it < 4; ++it)
#pragma unroll
      for (int kt = 0; kt < 2; ++kt)
#pragma unroll
        for (int j = 0; j < 8; ++j)
          Wf[it][kt][j] =
              (f16)wh[(size_t)(kt * 32 + lg * 8 + j) * DH + it * 16 + lr];

    // same-wave RAW through global: drain previous module's y stores
    asm volatile("s_waitcnt vmcnt(0)" ::: "memory");

    // prologue: mix(0) ready in mixf, pf holds chunk 1
    prefetch(m, 0);
    stage(m);
    prefetch(m, 1);
    gemm_issue();
    scatter();
    asm volatile("s_waitcnt lgkmcnt(0)" ::: "memory");
    mixload();

    for (int ch = 0; ch < NCH; ++ch) {
      const bool more = (ch + 1 < NCH);
      if (more) {
        stage(m);                            // chunk ch+1 (pf from prev iter)
        if (ch + 2 < NCH) prefetch(m, ch + 2);
        gemm_issue();                        // MFMAs retire in scan's shadow
        __builtin_amdgcn_sched_barrier(0);   // pin MFMAs before the scan
      }
      scan(m, ch);                           // serial chain (consumes mixf)
      if (more) {
        scatter();                           // acc(ch+1) -> MX
        asm volatile("s_waitcnt lgkmcnt(0)" ::: "memory");
        mixload();                           // mixf <- mix(ch+1)
      }
    }
  }

  float* ya = out + (size_t)B * T * D;
  ya[((size_t)b * NC + c) * D + h * DH + lane] = y;
}

// ---- expand (fallback path): y f16 (first 2KB of row) -> f32 rows ----
__global__ __launch_bounds__(256)
void expand(float* __restrict__ buf) {
  __shared__ __align__(16) f16 rs[4 * 1024];
  const int tid = threadIdx.x;
  unsigned char* const base = (unsigned char*)buf + (size_t)blockIdx.x * 4 * 4096;
#pragma unroll
  for (int p = 0; p < 2; ++p) {
    const int gid = p * 256 + tid;
    const int row = gid >> 7, c16 = gid & 127;
    *(uint4v*)((unsigned char*)rs + row * 2048 + c16 * 16) =
        *(const uint4v*)(base + (size_t)row * 4096 + c16 * 16);
  }
  __syncthreads();
#pragma unroll
  for (int p = 0; p < 4; ++p) {
    const int gid = p * 256 + tid;
    const int row = gid >> 8, c4 = gid & 255;
    const half4v hv = *(const half4v*)((unsigned char*)rs + row * 2048 + c4 * 8);
    f32x4 v;
#pragma unroll
    for (int e = 0; e < 4; ++e) v[e] = (float)hv[e];
    *(f32x4*)(base + (size_t)row * 4096 + c4 * 16) = v;
  }
}

extern "C" void kernel_launch(void* const* d_in, const int* in_sizes, int n_in,
                              void* d_out, int out_size, void* d_ws, size_t ws_size,
                              hipStream_t stream) {
  (void)in_sizes; (void)n_in; (void)out_size;
  const float* x  = (const float*)d_in[0];
  const float* xa = (const float*)d_in[1];
  const float* w  = (const float*)d_in[2];
  float* out = (float*)d_out;

  const bool usews = (d_ws != nullptr) && (ws_size >= YWS_BYTES);
  if (usews) {
    hipLaunchKernelGGL((ncn_wave<true>), dim3(256), dim3(256), 0, stream,
                       x, xa, w, out, (unsigned char*)d_ws);
  } else {
    hipLaunchKernelGGL((ncn_wave<false>), dim3(256), dim3(256), 0, stream,
                       x, xa, w, out, (unsigned char*)out);
    hipLaunchKernelGGL(expand, dim3(B * T / 4), dim3(256), 0, stream, out);
  }
}

// Round 18
// 135.354 us; speedup vs baseline: 1.0112x; 1.0112x over previous
//
#include <hip/hip_runtime.h>
#include <hip/hip_fp16.h>

// NCN producer/consumer wave pairs: 1024 chains (b,h,c), each = {gemm wave,
// scan wave} on one CU, coupled via 2-slot MX ring + LDS spin flags. 2048
// waves -> 2/SIMD: gemm latency hides under the partner's serial tanh chain
// via TLP (R16 showed single-wave ILP cannot). No __syncthreads except flag
// init. y handoff f16 in d_ws (module 3 writes f32 directly to d_out).
// Flags: gp (mix slot ready, after lgkm drain), sp_mx (slot consumed),
// sp_y (y stores vmcnt-drained -> visible to gemm wave's global reads).
// Fallback small-ws: y f16 in d_out row first-halves + expand kernel.
// MFMA mapping, swizzles, numerics = R15/R16-validated.

typedef _Float16 f16;
typedef _Float16 half8 __attribute__((ext_vector_type(8)));
typedef float f32x4 __attribute__((ext_vector_type(4)));
typedef unsigned uint4v __attribute__((ext_vector_type(4)));

constexpr int B = 8, T = 4096, D = 1024, H = 16, DH = 64, NC = 8, NM = 4;
constexpr int KS = 32;               // scan steps per chunk
constexpr int NCH = 16;              // chunks per module
constexpr int NG = NM * NCH;         // 64 global chunk indices
constexpr size_t YWS_BYTES = (size_t)B * T * 2048;   // 64 MiB
constexpr float L2E = 1.44269504088896340736f;

__device__ __forceinline__ float exp2_fast(float v) {
  float r;
  asm("v_exp_f32 %0, %1" : "=v"(r) : "v"(v));
  return r;
}

template <bool WS>
__global__ __launch_bounds__(256, 2)
void ncn_pair(const float* __restrict__ x, const float* __restrict__ xa,
              const float* __restrict__ w, float* __restrict__ out,
              unsigned char* __restrict__ ybuf) {
  constexpr int YROW = WS ? 2048 : 4096;   // y f16 row stride
  __shared__ __align__(16) unsigned char YST[2][4096];      // per-pair staged
  __shared__ __align__(16) unsigned char MXS[2][2][8192];   // per-pair 2-slot
  __shared__ int FLG[2][4];                // [pair]{gp, sp_mx, sp_y, pad}

  const int tid = threadIdx.x, lane = tid & 63, wv = tid >> 6;
  const int pair = wv >> 1;
  const bool gemmw = (wv & 1) == 0;
  const int g = blockIdx.x * 2 + pair;     // chain id 0..1023
  const int c = g & 7, h = (g >> 3) & 15, b = g >> 7;
  const int lr = lane & 15, lg = lane >> 4;

  const unsigned char* const xb = (const unsigned char*)x + (size_t)b * T * 4096;
  unsigned char* const ob = (unsigned char*)out + (size_t)b * T * 4096;
  unsigned char* const yb = ybuf + (size_t)b * T * YROW;

  if (tid < 8) ((int*)FLG)[tid] = 0;
  __syncthreads();                         // the only barrier (flag init)

  int* const fgp = &FLG[pair][0];
  int* const fmx = &FLG[pair][1];
  int* const fy  = &FLG[pair][2];

  auto waitge = [&](int* f, int v) {
    while (__hip_atomic_load(f, __ATOMIC_ACQUIRE,
                             __HIP_MEMORY_SCOPE_WORKGROUP) < v)
      __builtin_amdgcn_s_sleep(1);
  };
  auto signal = [&](int* f, int v) {
    if (lane == 0)
      __hip_atomic_store(f, v, __ATOMIC_RELEASE, __HIP_MEMORY_SCOPE_WORKGROUP);
  };

  if (gemmw) {
    // ================= producer: prefetch -> stage -> MFMA -> MX =========
    unsigned char* const yst = YST[pair];
    uint4v pf[8];
    half8 Wf[4][2];

    auto prefetch = [&](int Gn) {
      if (Gn >= NG) return;
      const int m = Gn >> 4, ch = Gn & 15;
      if (m >= 1) waitge(fy, (m - 1) * 16 + ch + 1);   // y visible in global
      const int J0 = ch * KS;
      if (m == 0) {                        // x f32: 32 rows x 256B
#pragma unroll
        for (int i = 0; i < 8; ++i) {
          const int lt = i * 4 + (lane >> 4);
          const int t = (J0 + lt) * 8 + c;
          pf[i] = *(const uint4v*)(xb + (size_t)t * 4096 + h * 256 +
                                   (lane & 15) * 16);
        }
      } else {                             // y f16: 32 rows x 128B
#pragma unroll
        for (int i = 0; i < 4; ++i) {
          const int lt = i * 8 + (lane >> 3);
          const int t = (J0 + lt) * 8 + c;
          pf[i] = *(const uint4v*)(yb + (size_t)t * YROW + h * 128 +
                                   (lane & 7) * 16);
        }
      }
    };
    auto stage = [&](int m) {              // pf -> yst (swizzled f16 rows)
      if (m == 0) {
#pragma unroll
        for (int i = 0; i < 8; ++i) {
          const int lt = i * 4 + (lane >> 4);
          const f32x4 v = __builtin_bit_cast(f32x4, pf[i]);
          const __half2 p0 = __floats2half2_rn(v.x, v.y);
          const __half2 p1 = __floats2half2_rn(v.z, v.w);
          uint2 pk;
          pk.x = __builtin_bit_cast(unsigned, p0);
          pk.y = __builtin_bit_cast(unsigned, p1);
          *(uint2*)(yst + lt * 128 + (((lane & 15) * 8) ^ ((lt & 7) << 4))) = pk;
        }
      } else {
#pragma unroll
        for (int i = 0; i < 4; ++i) {
          const int lt = i * 8 + (lane >> 3);
          *(uint4v*)(yst + lt * 128 + (((lane & 7) * 16) ^ ((lt & 7) << 4))) =
              pf[i];
        }
      }
    };

    prefetch(0);
    for (int G = 0; G < NG; ++G) {
      const int m = G >> 4, ch = G & 15;
      if (ch == 0) {                       // W frags (R8-validated mapping)
        const float* wh = w + ((size_t)m * H + h) * DH * DH;
#pragma unroll
        for (int it = 0; it < 4; ++it)
#pragma unroll
          for (int kt = 0; kt < 2; ++kt)
#pragma unroll
            for (int j = 0; j < 8; ++j)
              Wf[it][kt][j] =
                  (f16)wh[(size_t)(kt * 32 + lg * 8 + j) * DH + it * 16 + lr];
      }
      stage(m);
      prefetch(G + 1);

      f32x4 acc[2][4];
#pragma unroll
      for (int tq = 0; tq < 2; ++tq) {
        half8 Xf[2];
#pragma unroll
        for (int kt = 0; kt < 2; ++kt) {
          const int lt = tq * 16 + lr;
          Xf[kt] = *(const half8*)(yst + lt * 128 +
                                   ((kt * 64 + lg * 16) ^ ((lt & 7) << 4)));
        }
#pragma unroll
        for (int it = 0; it < 4; ++it) acc[tq][it] = (f32x4){0.f, 0.f, 0.f, 0.f};
#pragma unroll
        for (int kt = 0; kt < 2; ++kt)
#pragma unroll
          for (int it = 0; it < 4; ++it)
            acc[tq][it] = __builtin_amdgcn_mfma_f32_16x16x32_f16(
                Xf[kt], Wf[it][kt], acc[tq][it], 0, 0, 0);
      }

      waitge(fmx, G - 1);                  // MX slot G&1 free
      unsigned char* const mxs = MXS[pair][G & 1];
#pragma unroll
      for (int tq = 0; tq < 2; ++tq)
#pragma unroll
        for (int it = 0; it < 4; ++it) {
          const int e = it * 16 + lr;
          const __half2 p0 = __floats2half2_rn(acc[tq][it].x, acc[tq][it].y);
          const __half2 p1 = __floats2half2_rn(acc[tq][it].z, acc[tq][it].w);
          uint2 pk;
          pk.x = __builtin_bit_cast(unsigned, p0);
          pk.y = __builtin_bit_cast(unsigned, p1);
          *(uint2*)(mxs + e * 128 + ((tq * 32 + lg * 8) ^ ((e & 7) << 4))) = pk;
        }
      asm volatile("s_waitcnt lgkmcnt(0)" ::: "memory");
      signal(fgp, G + 1);                  // mix(G) ready
    }
  } else {
    // ================= consumer: mixload -> serial scan -> y stores ======
    float y = xa[((size_t)b * NC + c) * D + h * DH + lane];
    float u = y * L2E;
    float mixf[KS];

    for (int G = 0; G < NG; ++G) {
      const int m = G >> 4, ch = G & 15;
      waitge(fgp, G + 1);                  // mix(G) ready
      const unsigned char* const mxs = MXS[pair][G & 1];
      half8 mxr[4];
#pragma unroll
      for (int k16 = 0; k16 < 4; ++k16)
        mxr[k16] = *(const half8*)(mxs + lane * 128 +
                                   ((k16 * 16) ^ ((lane & 7) << 4)));
#pragma unroll
      for (int k = 0; k < KS; ++k) mixf[k] = (float)mxr[k >> 3][k & 7] * L2E;
      asm volatile("s_waitcnt lgkmcnt(0)" ::: "memory");
      signal(fmx, G + 1);                  // slot consumed

      const int t0 = ch * KS * 8 + c;
      if (m < 3 || !WS) {                  // y f16 -> ybuf rows
        unsigned char* sp = yb + (size_t)t0 * YROW + h * 128 + 2 * lane;
#pragma unroll
        for (int k = 0; k < KS; ++k) {
          const float z = u + mixf[k];     // tanh(0.5(cache+mix)), base-2
          const float E = exp2_fast(z);
          const float r = __builtin_amdgcn_rcpf(E + 1.0f);
          y = fmaf(r, -2.0f, 1.0f);
          u = fmaf(r, -2.0f * L2E, L2E);
          *(__half*)sp = __float2half_rn(y);
          sp += (size_t)8 * YROW;
        }
      } else {                             // module 3 (ws path): f32 -> d_out
        unsigned char* sp = ob + (size_t)t0 * 4096 + h * 256 + 4 * lane;
#pragma unroll
        for (int k = 0; k < KS; ++k) {
          const float z = u + mixf[k];
          const float E = exp2_fast(z);
          const float r = __builtin_amdgcn_rcpf(E + 1.0f);
          y = fmaf(r, -2.0f, 1.0f);
          u = fmaf(r, -2.0f * L2E, L2E);
          *(float*)sp = y;
          sp += (size_t)8 * 4096;
        }
      }
      asm volatile("s_waitcnt vmcnt(0)" ::: "memory");
      signal(fy, G + 1);                   // y(G) visible in global
    }

    float* ya = out + (size_t)B * T * D;
    ya[((size_t)b * NC + c) * D + h * DH + lane] = y;
  }
}

// ---- expand (fallback path): y f16 (first 2KB of row) -> f32 rows ----
__global__ __launch_bounds__(256)
void expand(float* __restrict__ buf) {
  typedef _Float16 half4v __attribute__((ext_vector_type(4)));
  __shared__ __align__(16) f16 rs[4 * 1024];
  const int tid = threadIdx.x;
  unsigned char* const base = (unsigned char*)buf + (size_t)blockIdx.x * 4 * 4096;
#pragma unroll
  for (int p = 0; p < 2; ++p) {
    const int gid = p * 256 + tid;
    const int row = gid >> 7, c16 = gid & 127;
    *(uint4v*)((unsigned char*)rs + row * 2048 + c16 * 16) =
        *(const uint4v*)(base + (size_t)row * 4096 + c16 * 16);
  }
  __syncthreads();
#pragma unroll
  for (int p = 0; p < 4; ++p) {
    const int gid = p * 256 + tid;
    const int row = gid >> 8, c4 = gid & 255;
    const half4v hv = *(const half4v*)((unsigned char*)rs + row * 2048 + c4 * 8);
    f32x4 v;
#pragma unroll
    for (int e = 0; e < 4; ++e) v[e] = (float)hv[e];
    *(f32x4*)(base + (size_t)row * 4096 + c4 * 16) = v;
  }
}

extern "C" void kernel_launch(void* const* d_in, const int* in_sizes, int n_in,
                              void* d_out, int out_size, void* d_ws, size_t ws_size,
                              hipStream_t stream) {
  (void)in_sizes; (void)n_in; (void)out_size;
  const float* x  = (const float*)d_in[0];
  const float* xa = (const float*)d_in[1];
  const float* w  = (const float*)d_in[2];
  float* out = (float*)d_out;

  const bool usews = (d_ws != nullptr) && (ws_size >= YWS_BYTES);
  if (usews) {
    hipLaunchKernelGGL((ncn_pair<true>), dim3(512), dim3(256), 0, stream,
                       x, xa, w, out, (unsigned char*)d_ws);
  } else {
    hipLaunchKernelGGL((ncn_pair<false>), dim3(512), dim3(256), 0, stream,
                       x, xa, w, out, (unsigned char*)out);
    hipLaunchKernelGGL(expand, dim3(B * T / 4), dim3(256), 0, stream, out);
  }
}